// Round 3
// baseline (82.172 us; speedup 1.0000x reference)
//
#include <hip/hip_runtime.h>
#include <hip/hip_bf16.h>

#define N_ROWS 32768
#define K_DIM 512
#define OUT_DIM 512
#define N_TYPES 8

#define BM 128
#define BN 128
#define BK 64

typedef __attribute__((ext_vector_type(8))) short bf16x8;
typedef __attribute__((ext_vector_type(4))) float f32x4;

__device__ inline ushort f2bf(float f) {
    __hip_bfloat16 h = __float2bfloat16(f);
    return *reinterpret_cast<ushort*>(&h);
}

__device__ inline void gload_lds16(const void* g, void* l) {
    __builtin_amdgcn_global_load_lds(
        (const __attribute__((address_space(1))) void*)g,
        (__attribute__((address_space(3))) void*)l, 16, 0, 0);
}

// meta layout (ints): [0..7] counts, [8..15] bases, [16..23] cursors
__global__ void k_init(int* meta) {
    if (threadIdx.x < 24) meta[threadIdx.x] = 0;
}

// per-block LDS histogram -> 8 global atomics per block
__global__ void k_hist(const int* __restrict__ x_type, int* meta) {
    __shared__ int cnt[N_TYPES];
    if (threadIdx.x < N_TYPES) cnt[threadIdx.x] = 0;
    __syncthreads();
    int i = blockIdx.x * 256 + threadIdx.x;
    atomicAdd(&cnt[x_type[i]], 1);
    __syncthreads();
    if (threadIdx.x < N_TYPES && cnt[threadIdx.x] > 0)
        atomicAdd(&meta[threadIdx.x], cnt[threadIdx.x]);
}

__global__ void k_scan(int* meta) {
    if (threadIdx.x == 0) {
        int s = 0;
        for (int t = 0; t < N_TYPES; ++t) {
            meta[8 + t] = s;          // base
            meta[16 + t] = s;         // absolute cursor
            s += meta[t];
        }
    }
}

// per-block LDS hist -> reserve range with 8 global atomics -> scatter
__global__ void k_fill(const int* __restrict__ x_type, int* meta, int* __restrict__ row_ids) {
    __shared__ int lcnt[N_TYPES];
    __shared__ int lbase[N_TYPES];
    if (threadIdx.x < N_TYPES) lcnt[threadIdx.x] = 0;
    __syncthreads();
    int i = blockIdx.x * 256 + threadIdx.x;
    int t = x_type[i];
    int lpos = atomicAdd(&lcnt[t], 1);
    __syncthreads();
    if (threadIdx.x < N_TYPES)
        lbase[threadIdx.x] = (lcnt[threadIdx.x] > 0)
            ? atomicAdd(&meta[16 + threadIdx.x], lcnt[threadIdx.x]) : 0;
    __syncthreads();
    row_ids[lbase[t] + lpos] = i;
}

// gather x rows into sorted order + fp32 -> bf16.  4 rows/block, 64 thr/row.
__global__ __launch_bounds__(256) void k_gather(const float* __restrict__ x,
        const int* __restrict__ row_ids, ushort* __restrict__ xs) {
    int p = blockIdx.x * 4 + (threadIdx.x >> 6);
    int l = threadIdx.x & 63;
    int rid = row_ids[p];
    const float* src = x + (size_t)rid * K_DIM + l * 8;
    float4 v0 = *reinterpret_cast<const float4*>(src);
    float4 v1 = *reinterpret_cast<const float4*>(src + 4);
    ushort tmp[8] = { f2bf(v0.x), f2bf(v0.y), f2bf(v0.z), f2bf(v0.w),
                      f2bf(v1.x), f2bf(v1.y), f2bf(v1.z), f2bf(v1.w) };
    *reinterpret_cast<uint4*>(xs + (size_t)p * K_DIM + l * 8) =
        *reinterpret_cast<uint4*>(tmp);
}

// W[t][k][c] fp32 -> Wt[t][c][k] bf16   (64x64 tiles through LDS)
__global__ void k_wt(const float* __restrict__ W, ushort* __restrict__ Wt) {
    __shared__ float tile[64][65];
    int t = blockIdx.x, kb = blockIdx.y, cb = blockIdx.z;
    const float* src = W + (size_t)t * K_DIM * OUT_DIM + (size_t)kb * 64 * OUT_DIM + cb * 64;
    #pragma unroll
    for (int j = 0; j < 16; ++j) {
        int idx = threadIdx.x + j * 256;
        int r = idx >> 6, c = idx & 63;
        tile[r][c] = src[(size_t)r * OUT_DIM + c];
    }
    __syncthreads();
    ushort* dst = Wt + (size_t)t * OUT_DIM * K_DIM + (size_t)(cb * 64) * K_DIM + kb * 64;
    #pragma unroll
    for (int j = 0; j < 16; ++j) {
        int idx = threadIdx.x + j * 256;
        int cc = idx >> 6, kk = idx & 63;
        dst[(size_t)cc * K_DIM + kk] = f2bf(tile[kk][cc]);
    }
}

// m97-structure GEMM: bf16 sorted xs, global_load_lds staging, BK=64.
__global__ __launch_bounds__(256) void k_gemm2(
    const ushort* __restrict__ xs, const ushort* __restrict__ Wt,
    const int* __restrict__ meta, const int* __restrict__ row_ids,
    float* __restrict__ out) {

    __shared__ ushort As[BM * BK];   // [row][k] linear (global_load_lds dest)
    __shared__ ushort Bs[BN * BK];   // [col][k] linear
    __shared__ int rids[BM];

    // map blockIdx.x -> (type, row-tile)
    int b = blockIdx.x;
    int type = -1, mt = 0, acc_tiles = 0;
    for (int t = 0; t < N_TYPES; ++t) {
        int cnt_t = meta[t];
        int nt = (cnt_t + BM - 1) / BM;
        if (b < acc_tiles + nt) { type = t; mt = b - acc_tiles; break; }
        acc_tiles += nt;
    }
    if (type < 0) return;

    int cnt  = meta[type];
    int base = meta[8 + type];
    int row0 = mt * BM;
    int nrows = min(BM, cnt - row0);
    int srow0 = base + row0;         // sorted-row base of this tile

    int tid = threadIdx.x;
    if (tid < BM) rids[tid] = (tid < nrows) ? row_ids[base + row0 + tid] : -1;

    int c0 = blockIdx.y * BN;
    const ushort* Wtt = Wt + (size_t)type * OUT_DIM * K_DIM + (size_t)c0 * K_DIM;

    f32x4 acc[4][4] = {};

    int wave = tid >> 6, lane = tid & 63;
    int wr = (wave >> 1) * 64;       // wave row base in tile
    int wc = (wave & 1) * 64;        // wave col base in tile
    int lrow = lane & 15;
    int lkb = (lane >> 4) * 8;       // k elem offset within a 32-wide subtile

    // staging geometry: chunk c covers rows c*8..c*8+7 (1 KB), lane -> 16 B
    int st_r = lane >> 3;            // row within chunk
    int st_c = (lane & 7) * 8;       // k elem offset

    for (int kk = 0; kk < K_DIM; kk += BK) {
        #pragma unroll
        for (int j = 0; j < 4; ++j) {
            int c = wave * 4 + j;
            int ar = srow0 + c * 8 + st_r;
            if (ar > N_ROWS - 1) ar = N_ROWS - 1;   // clamp padding rows
            gload_lds16(xs + (size_t)ar * K_DIM + kk + st_c, &As[c * 512]);
            gload_lds16(Wtt + (size_t)(c * 8 + st_r) * K_DIM + kk + st_c, &Bs[c * 512]);
        }
        __syncthreads();   // compiler emits vmcnt(0) drain before barrier

        #pragma unroll
        for (int s = 0; s < 2; ++s) {
            bf16x8 af[4], bfr[4];
            #pragma unroll
            for (int mi = 0; mi < 4; ++mi)
                af[mi] = *reinterpret_cast<const bf16x8*>(&As[(wr + mi * 16 + lrow) * BK + s * 32 + lkb]);
            #pragma unroll
            for (int ni = 0; ni < 4; ++ni)
                bfr[ni] = *reinterpret_cast<const bf16x8*>(&Bs[(wc + ni * 16 + lrow) * BK + s * 32 + lkb]);
            #pragma unroll
            for (int mi = 0; mi < 4; ++mi)
                #pragma unroll
                for (int ni = 0; ni < 4; ++ni)
                    acc[mi][ni] = __builtin_amdgcn_mfma_f32_16x16x32_bf16(af[mi], bfr[ni], acc[mi][ni], 0, 0, 0);
        }
        __syncthreads();
    }

    // epilogue: D row = (lane>>4)*4 + rr, col = lane&15   [guide §3, m89/m91]
    int rgrp = (lane >> 4) * 4;
    #pragma unroll
    for (int mi = 0; mi < 4; ++mi) {
        #pragma unroll
        for (int rr = 0; rr < 4; ++rr) {
            int lr = wr + mi * 16 + rgrp + rr;
            int gr = rids[lr];
            if (gr >= 0) {
                float* dst = out + (size_t)gr * OUT_DIM + c0 + wc;
                #pragma unroll
                for (int ni = 0; ni < 4; ++ni)
                    dst[ni * 16 + lrow] = acc[mi][ni][rr];
            }
        }
    }
}

// ---------------- fallback (round-2 kernel, used if ws too small) ----------
__global__ __launch_bounds__(256) void k_gemm_fb(
    const float* __restrict__ x, const ushort* __restrict__ Wt,
    const int* __restrict__ meta, const int* __restrict__ row_ids,
    float* __restrict__ out) {

    __shared__ ushort As[BM][32];
    __shared__ ushort Bs[BN][32];
    __shared__ int rids[BM];

    int b = blockIdx.x;
    int type = -1, mt = 0, acc_tiles = 0;
    for (int t = 0; t < N_TYPES; ++t) {
        int cnt_t = meta[t];
        int nt = (cnt_t + BM - 1) / BM;
        if (b < acc_tiles + nt) { type = t; mt = b - acc_tiles; break; }
        acc_tiles += nt;
    }
    if (type < 0) return;

    int cnt  = meta[type];
    int base = meta[8 + type];
    int row0 = mt * BM;
    int nrows = min(BM, cnt - row0);

    int tid = threadIdx.x;
    if (tid < BM) rids[tid] = (tid < nrows) ? row_ids[base + row0 + tid] : -1;
    __syncthreads();

    int c0 = blockIdx.y * BN;
    const ushort* Wtt = Wt + (size_t)type * OUT_DIM * K_DIM + (size_t)c0 * K_DIM;

    f32x4 acc[4][4] = {};
    int wave = tid >> 6, lane = tid & 63;
    int wr = (wave >> 1) * 64, wc = (wave & 1) * 64;
    int lrow = lane & 15, lk = (lane >> 4) * 8;
    int sa_r = tid >> 1, sa_h = (tid & 1) * 16;

    for (int kk = 0; kk < K_DIM; kk += 32) {
        {
            int rid = rids[sa_r];
            ushort tmp[16];
            if (rid >= 0) {
                const float* src = x + (size_t)rid * K_DIM + kk + sa_h;
                #pragma unroll
                for (int j = 0; j < 16; j += 4) {
                    float4 v = *reinterpret_cast<const float4*>(src + j);
                    tmp[j + 0] = f2bf(v.x); tmp[j + 1] = f2bf(v.y);
                    tmp[j + 2] = f2bf(v.z); tmp[j + 3] = f2bf(v.w);
                }
            } else {
                #pragma unroll
                for (int j = 0; j < 16; ++j) tmp[j] = 0;
            }
            *reinterpret_cast<uint4*>(&As[sa_r][sa_h])     = *reinterpret_cast<uint4*>(&tmp[0]);
            *reinterpret_cast<uint4*>(&As[sa_r][sa_h + 8]) = *reinterpret_cast<uint4*>(&tmp[8]);
        }
        {
            int c = tid >> 1, h = (tid & 1) * 16;
            const ushort* src = Wtt + (size_t)c * K_DIM + kk + h;
            *reinterpret_cast<uint4*>(&Bs[c][h])     = *reinterpret_cast<const uint4*>(src);
            *reinterpret_cast<uint4*>(&Bs[c][h + 8]) = *reinterpret_cast<const uint4*>(src + 8);
        }
        __syncthreads();
        bf16x8 af[4], bfr[4];
        #pragma unroll
        for (int mi = 0; mi < 4; ++mi)
            af[mi] = *reinterpret_cast<const bf16x8*>(&As[wr + mi * 16 + lrow][lk]);
        #pragma unroll
        for (int ni = 0; ni < 4; ++ni)
            bfr[ni] = *reinterpret_cast<const bf16x8*>(&Bs[wc + ni * 16 + lrow][lk]);
        #pragma unroll
        for (int mi = 0; mi < 4; ++mi)
            #pragma unroll
            for (int ni = 0; ni < 4; ++ni)
                acc[mi][ni] = __builtin_amdgcn_mfma_f32_16x16x32_bf16(af[mi], bfr[ni], acc[mi][ni], 0, 0, 0);
        __syncthreads();
    }

    int rgrp = (lane >> 4) * 4;
    #pragma unroll
    for (int mi = 0; mi < 4; ++mi) {
        #pragma unroll
        for (int rr = 0; rr < 4; ++rr) {
            int lr = wr + mi * 16 + rgrp + rr;
            int gr = rids[lr];
            if (gr >= 0) {
                float* dst = out + (size_t)gr * OUT_DIM + c0 + wc;
                #pragma unroll
                for (int ni = 0; ni < 4; ++ni)
                    dst[ni * 16 + lrow] = acc[mi][ni][rr];
            }
        }
    }
}

extern "C" void kernel_launch(void* const* d_in, const int* in_sizes, int n_in,
                              void* d_out, int out_size, void* d_ws, size_t ws_size,
                              hipStream_t stream) {
    const float* x      = (const float*)d_in[0];
    const int*   x_type = (const int*)d_in[1];
    const float* W      = (const float*)d_in[2];
    float* out          = (float*)d_out;

    // workspace layout
    char* ws = (char*)d_ws;
    size_t off_rids = 256;
    size_t off_wt   = off_rids + sizeof(int) * N_ROWS;                    // 131328
    size_t off_xs   = off_wt + (size_t)N_TYPES * K_DIM * OUT_DIM * 2;     // 4325632
    size_t need     = off_xs + (size_t)N_ROWS * K_DIM * 2;                // ~36.1 MB

    int* meta    = (int*)ws;
    int* row_ids = (int*)(ws + off_rids);
    ushort* Wt   = (ushort*)(ws + off_wt);
    ushort* xs   = (ushort*)(ws + off_xs);

    k_init<<<1, 64, 0, stream>>>(meta);
    k_hist<<<N_ROWS / 256, 256, 0, stream>>>(x_type, meta);
    k_scan<<<1, 64, 0, stream>>>(meta);
    k_fill<<<N_ROWS / 256, 256, 0, stream>>>(x_type, meta, row_ids);

    dim3 wgrid(N_TYPES, K_DIM / 64, OUT_DIM / 64);
    k_wt<<<wgrid, 256, 0, stream>>>(W, Wt);

    dim3 ggrid(N_ROWS / BM + N_TYPES, OUT_DIM / BN);
    if (ws_size >= need) {
        k_gather<<<N_ROWS / 4, 256, 0, stream>>>(x, row_ids, xs);
        k_gemm2<<<ggrid, 256, 0, stream>>>(xs, Wt, meta, row_ids, out);
    } else {
        k_gemm_fb<<<ggrid, 256, 0, stream>>>(x, Wt, meta, row_ids, out);
    }
}